// Round 1
// baseline (400.880 us; speedup 1.0000x reference)
//
#include <hip/hip_runtime.h>
#include <math.h>

#define S_DIM 512
#define B_DIM 128
#define H_DIM 512
#define T_DIM 48

// ---------------------------------------------------------------------------
// K1: emissions[s,b,t] = wf[s,b,:] . W[t,:] + bias[t]
// 256 blocks x 256 threads; each block computes 256 rows x 48 cols.
// Per thread: 8 rows (strided by 32) x 6 cols register tile.
// Also zeroes out[0] (nll accumulator) from block 0.
// ---------------------------------------------------------------------------
__global__ __launch_bounds__(256) void k_emissions(
    const float* __restrict__ wf, const float* __restrict__ W,
    const float* __restrict__ bias, float* __restrict__ em,
    float* __restrict__ out)
{
  if (blockIdx.x == 0 && threadIdx.x == 0) out[0] = 0.0f;

  // padded stride 36: rows differ by 32*r across a lane's tile; lanes in a
  // wave differ in rgrp (0..7): (rgrp*36) % 32 = 4*rgrp -> conflict-free.
  __shared__ float wfs[256][36];
  __shared__ float Ws[48][36];

  const int tid  = threadIdx.x;
  const int cgrp = tid & 7;    // 0..7 -> cols cgrp*6 .. +5
  const int rgrp = tid >> 3;   // 0..31 -> rows rgrp + 32*r
  const int row0 = blockIdx.x << 8;

  float acc[8][6];
#pragma unroll
  for (int r = 0; r < 8; ++r)
#pragma unroll
    for (int c = 0; c < 6; ++c) acc[r][c] = 0.0f;

  for (int hc = 0; hc < H_DIM; hc += 32) {
    __syncthreads();  // protect LDS from previous iteration's readers
    // stage wf tile: 256 rows x 32 h = 2048 float4, 8 per thread
#pragma unroll
    for (int k = 0; k < 8; ++k) {
      int f  = tid + (k << 8);
      int r  = f >> 3;
      int ho = (f & 7) << 2;
      float4 v = *(const float4*)&wf[(size_t)(row0 + r) * H_DIM + hc + ho];
      *(float4*)&wfs[r][ho] = v;
    }
    // stage W tile: 48 rows x 32 h = 384 float4
    {
      int r  = tid >> 3;
      int ho = (tid & 7) << 2;
      *(float4*)&Ws[r][ho] = *(const float4*)&W[(size_t)r * H_DIM + hc + ho];
      if (tid < 128) {
        int f   = 256 + tid;
        int r2  = f >> 3;
        int ho2 = (f & 7) << 2;
        *(float4*)&Ws[r2][ho2] = *(const float4*)&W[(size_t)r2 * H_DIM + hc + ho2];
      }
    }
    __syncthreads();

#pragma unroll
    for (int h = 0; h < 32; h += 4) {
      float4 a[8], w[6];
#pragma unroll
      for (int r = 0; r < 8; ++r) a[r] = *(const float4*)&wfs[rgrp + 32 * r][h];
#pragma unroll
      for (int c = 0; c < 6; ++c) w[c] = *(const float4*)&Ws[cgrp * 6 + c][h];
#pragma unroll
      for (int r = 0; r < 8; ++r)
#pragma unroll
        for (int c = 0; c < 6; ++c) {
          acc[r][c] = fmaf(a[r].x, w[c].x, acc[r][c]);
          acc[r][c] = fmaf(a[r].y, w[c].y, acc[r][c]);
          acc[r][c] = fmaf(a[r].z, w[c].z, acc[r][c]);
          acc[r][c] = fmaf(a[r].w, w[c].w, acc[r][c]);
        }
    }
  }

  float bb[6];
#pragma unroll
  for (int c = 0; c < 6; ++c) bb[c] = bias[cgrp * 6 + c];

#pragma unroll
  for (int r = 0; r < 8; ++r) {
    int row = row0 + rgrp + 32 * r;
    float* dst = &em[(size_t)row * T_DIM + cgrp * 6];
#pragma unroll
    for (int c = 0; c < 6; c += 2) {
      float2 v = make_float2(acc[r][c] + bb[c], acc[r][c + 1] + bb[c + 1]);
      *(float2*)&dst[c] = v;
    }
  }
}

// ---------------------------------------------------------------------------
// K2: forward scan in scaled linear space.
// alpha_s[j] = log(u_s[j]) + ktot*ln2 ;  u' = (u^T . expT) * exp(emit_s),
// rescaled by an exact power of 2 every step.
// One block (1 wave, 64 lanes) per batch element; lane = output tag j.
// expT[:,j] lives in 48 VGPRs; u broadcast via LDS (uniform float4 reads).
// ---------------------------------------------------------------------------
__global__ __launch_bounds__(64) void k_scan(
    const float* __restrict__ em, const float* __restrict__ trans,
    float* __restrict__ logZ)
{
  const int b    = blockIdx.x;
  const int lane = threadIdx.x;
  const int j    = lane < T_DIM ? lane : (T_DIM - 1);

  __shared__ __align__(16) float ush[64];

  float expTT[48];
#pragma unroll
  for (int i = 0; i < 48; ++i) expTT[i] = __expf(trans[i * T_DIM + j]);

  // s = 0: u = exp(emissions[0,b,j])
  float u    = __expf(em[(size_t)b * T_DIM + j]);
  int   ktot = 0;
  float enext = em[(size_t)(B_DIM + b) * T_DIM + j];  // prefetch s=1

  for (int s = 1; s < S_DIM; ++s) {
    ush[lane] = u;
    __syncthreads();

    float ee = __expf(enext);
    if (s < S_DIM - 1)
      enext = em[(size_t)((s + 1) * B_DIM + b) * T_DIM + j];

    float a0 = 0.f, a1 = 0.f, a2 = 0.f, a3 = 0.f;
#pragma unroll
    for (int m = 0; m < 12; ++m) {
      float4 uv = *(const float4*)&ush[4 * m];
      a0 = fmaf(uv.x, expTT[4 * m + 0], a0);
      a1 = fmaf(uv.y, expTT[4 * m + 1], a1);
      a2 = fmaf(uv.z, expTT[4 * m + 2], a2);
      a3 = fmaf(uv.w, expTT[4 * m + 3], a3);
    }
    float un = ((a0 + a1) + (a2 + a3)) * ee;

    // exact power-of-2 rescale, uniform across the wave
    float f0 = __builtin_amdgcn_readfirstlane(un);
    int ex;
    frexpf(f0, &ex);
    u = ldexpf(un, -ex);
    ktot += ex;
    __syncthreads();  // readers done before next write
  }

  float uu = (lane < T_DIM) ? u : 0.0f;
#pragma unroll
  for (int off = 32; off; off >>= 1) uu += __shfl_xor(uu, off, 64);
  if (lane == 0)
    logZ[b] = __logf(uu) + (float)ktot * 0.69314718055994531f;
}

// ---------------------------------------------------------------------------
// K3: gold path score + final NLL reduction.
// One block per batch element; atomicAdd the per-batch contribution.
// ---------------------------------------------------------------------------
__global__ __launch_bounds__(256) void k_gold(
    const float* __restrict__ em, const float* __restrict__ trans,
    const int* __restrict__ tags, const float* __restrict__ logZ,
    float* __restrict__ out)
{
  const int b = blockIdx.x;
  const int t = threadIdx.x;

  float g = 0.0f;
  for (int s = t; s < S_DIM; s += 256) {
    int tag = tags[s * B_DIM + b];
    g += em[(size_t)(s * B_DIM + b) * T_DIM + tag];
    if (s < S_DIM - 1) {
      int tagn = tags[(s + 1) * B_DIM + b];
      g += trans[tag * T_DIM + tagn];
    }
  }

  __shared__ float red[4];
#pragma unroll
  for (int off = 32; off; off >>= 1) g += __shfl_xor(g, off, 64);
  if ((t & 63) == 0) red[t >> 6] = g;
  __syncthreads();
  if (t == 0) {
    float gold = red[0] + red[1] + red[2] + red[3];
    atomicAdd(out, (logZ[b] - gold) * (1.0f / (float)B_DIM));
  }
}

// ---------------------------------------------------------------------------
extern "C" void kernel_launch(void* const* d_in, const int* in_sizes, int n_in,
                              void* d_out, int out_size, void* d_ws, size_t ws_size,
                              hipStream_t stream)
{
  const float* wf    = (const float*)d_in[0];  // [S,B,H]
  const float* W     = (const float*)d_in[1];  // [T,H]
  const float* bias  = (const float*)d_in[2];  // [T]
  const float* trans = (const float*)d_in[3];  // [T,T]
  const int*   tags  = (const int*)d_in[4];    // [S,B]
  float* out = (float*)d_out;

  float* em   = (float*)d_ws;                              // 12 MiB
  float* logZ = em + (size_t)S_DIM * B_DIM * T_DIM;        // 128 floats

  k_emissions<<<256, 256, 0, stream>>>(wf, W, bias, em, out);
  k_scan<<<B_DIM, 64, 0, stream>>>(em, trans, logZ);
  k_gold<<<B_DIM, 256, 0, stream>>>(em, trans, tags, logZ, out);
}

// Round 2
// 256.440 us; speedup vs baseline: 1.5633x; 1.5633x over previous
//
#include <hip/hip_runtime.h>
#include <math.h>

#define S_DIM 512
#define B_DIM 128
#define H_DIM 512
#define T_DIM 48

typedef short bf16x8 __attribute__((ext_vector_type(8)));   // 8 bf16 = 4 VGPR (MFMA A/B frag)
typedef short s16x4  __attribute__((ext_vector_type(4)));
typedef float f32x4  __attribute__((ext_vector_type(4)));   // MFMA C/D frag

__device__ __forceinline__ short rne_bf(float f) {  // fp32 -> bf16 round-nearest-even
  unsigned u = __float_as_uint(f);
  u += 0x7fffu + ((u >> 16) & 1u);
  return (short)(u >> 16);
}
__device__ __forceinline__ short trunc_bf(float f) {  // cheap truncation (hot path)
  return (short)(__float_as_uint(f) >> 16);
}

// ---------------------------------------------------------------------------
// Node format: 48x48 bf16, COLUMN-major: node[j*48 + k] = M[k][j], j,k < 48.
// Serves as the MFMA B operand: lane reads 8 consecutive k at fixed column j.
// ---------------------------------------------------------------------------
struct Frags6 { bf16x8 b[2][3]; };  // [kstep][coltile]

__device__ __forceinline__ void load_child(const short* __restrict__ p, int h, int q, Frags6& f) {
  bf16x8 z = 0;
#pragma unroll
  for (int ct = 0; ct < 3; ++ct) {
    const short* col = p + (16 * ct + q) * 48;
    f.b[0][ct] = *(const bf16x8*)(col + 8 * h);                       // k = 8h..8h+7 (<32)
    f.b[1][ct] = (h < 2) ? *(const bf16x8*)(col + 32 + 8 * h) : z;    // k = 32..47, zero for k>=48
  }
}

// one product step: C = A x B, A = (useI ? I48 : M in LDS), 18 MFMA
// Ml: [48 rows][64 k] bf16, short idx = row*64 + (k ^ ((row&7)<<3))  (XOR swizzle)
__device__ __forceinline__ void matstep(const short* Ml, bool useI, int h, int q,
                                        const Frags6& B, f32x4 C[3][3]) {
#pragma unroll
  for (int rt = 0; rt < 3; ++rt) {
    const int row = 16 * rt + q;
    bf16x8 a0, a1;
    if (useI) {
      const short one = (short)0x3F80;  // bf16 1.0
#pragma unroll
      for (int i = 0; i < 8; ++i) {
        a0[i] = (row == 8 * h + i) ? one : (short)0;
        a1[i] = (row == 32 + 8 * h + i) ? one : (short)0;
      }
    } else {
      const int sw = (row & 7) << 3;
      a0 = *(const bf16x8*)&Ml[row * 64 + ((8 * h) ^ sw)];
      a1 = *(const bf16x8*)&Ml[row * 64 + ((32 + 8 * h) ^ sw)];
    }
#pragma unroll
    for (int ct = 0; ct < 3; ++ct) {
      C[rt][ct] = __builtin_amdgcn_mfma_f32_16x16x32_bf16(a0, B.b[0][ct], C[rt][ct], 0, 0, 0);
      C[rt][ct] = __builtin_amdgcn_mfma_f32_16x16x32_bf16(a1, B.b[1][ct], C[rt][ct], 0, 0, 0);
    }
  }
}

// write C (fp32) back into M LDS as bf16.  D-frag: row = 16rt+4h+reg, col = 16ct+q.
__device__ __forceinline__ void writeM(short* Ml, int h, int q, const f32x4 C[3][3]) {
#pragma unroll
  for (int rt = 0; rt < 3; ++rt)
#pragma unroll
    for (int ct = 0; ct < 3; ++ct) {
      const int j = 16 * ct + q;
#pragma unroll
      for (int r = 0; r < 4; ++r) {
        const int row = 16 * rt + 4 * h + r;
        Ml[row * 64 + (j ^ ((row & 7) << 3))] = trunc_bf(C[rt][ct][r]);
      }
    }
}

// rescale C so max in [0.5,1), store as col-major node; returns exponent
__device__ __forceinline__ int store_node(short* __restrict__ node, int h, int q,
                                          const f32x4 C[3][3]) {
  float mx = 0.f;
#pragma unroll
  for (int rt = 0; rt < 3; ++rt)
#pragma unroll
    for (int ct = 0; ct < 3; ++ct)
#pragma unroll
      for (int r = 0; r < 4; ++r) mx = fmaxf(mx, C[rt][ct][r]);
#pragma unroll
  for (int off = 1; off < 64; off <<= 1) mx = fmaxf(mx, __shfl_xor(mx, off, 64));
  int ex;
  frexpf(mx, &ex);
  const float sc = ldexpf(1.0f, -ex);
#pragma unroll
  for (int rt = 0; rt < 3; ++rt)
#pragma unroll
    for (int ct = 0; ct < 3; ++ct) {
      s16x4 pk;
#pragma unroll
      for (int r = 0; r < 4; ++r) pk[r] = rne_bf(C[rt][ct][r] * sc);
      *(s16x4*)&node[(16 * ct + q) * 48 + 16 * rt + 4 * h] = pk;
    }
  return ex;
}

__device__ __forceinline__ void zero_lds(short* Ml, int l) {
  s16x4 z = 0;
#pragma unroll
  for (int i = 0; i < 12; ++i) *(s16x4*)&Ml[(l + 64 * i) * 4] = z;  // 48*64 shorts
}

// ---------------------------------------------------------------------------
// K0: prep — Wbf[j][k]=bf16(W[j,k]); expTcm[j*48+k]=bf16(exp(trans[k][j])); out=0
// ---------------------------------------------------------------------------
__global__ void k_prep(const float* __restrict__ W, const float* __restrict__ trans,
                       short* __restrict__ Wbf, short* __restrict__ expTcm,
                       float* __restrict__ out) {
  int idx = blockIdx.x * 256 + threadIdx.x;
  if (idx == 0) out[0] = 0.f;
  for (int i = idx; i < T_DIM * H_DIM; i += gridDim.x * 256) Wbf[i] = rne_bf(W[i]);
  for (int i = idx; i < T_DIM * T_DIM; i += gridDim.x * 256) {
    int j = i / 48, k = i - j * 48;
    expTcm[j * 48 + k] = rne_bf(__expf(trans[k * 48 + j]));
  }
}

// ---------------------------------------------------------------------------
// K1: emissions via bf16 MFMA. em[row][t] = wf[row,:] . W[t,:] + b[t], fp32 out.
// 512 blocks x 256 thr; block: 128 rows; wave w: rows 32w..32w+31 (2 rowtiles x 3 coltiles).
// ---------------------------------------------------------------------------
__global__ __launch_bounds__(256) void k_emissions(
    const float* __restrict__ wf, const short* __restrict__ Wbf,
    const float* __restrict__ bias, float* __restrict__ em) {
  __shared__ short A[128 * 32];  // bf16, swizzled: idx = row*32 + (k ^ ((row&3)<<3))
  const int tid = threadIdx.x;
  const int w = tid >> 6, l = tid & 63, h = l >> 4, q = l & 15;
  const int r0 = blockIdx.x * 128;
  const int trow = tid >> 3, tc4 = tid & 7;

  f32x4 C[2][3];
#pragma unroll
  for (int rt = 0; rt < 2; ++rt)
#pragma unroll
    for (int ct = 0; ct < 3; ++ct) C[rt][ct] = 0.f;

  for (int ks = 0; ks < 16; ++ks) {
    const int k0 = ks * 32;
    __syncthreads();
#pragma unroll
    for (int qq = 0; qq < 4; ++qq) {
      const int row = trow + 32 * qq;
      float4 v = *(const float4*)&wf[(size_t)(r0 + row) * H_DIM + k0 + 4 * tc4];
      s16x4 pk;
      pk[0] = rne_bf(v.x); pk[1] = rne_bf(v.y); pk[2] = rne_bf(v.z); pk[3] = rne_bf(v.w);
      *(s16x4*)&A[row * 32 + ((4 * tc4) ^ ((row & 3) << 3))] = pk;
    }
    __syncthreads();
    bf16x8 bfr[3];
#pragma unroll
    for (int ct = 0; ct < 3; ++ct)
      bfr[ct] = *(const bf16x8*)&Wbf[(size_t)(16 * ct + q) * H_DIM + k0 + 8 * h];
#pragma unroll
    for (int rt = 0; rt < 2; ++rt) {
      const int row = 32 * w + 16 * rt + q;
      bf16x8 a = *(const bf16x8*)&A[row * 32 + ((8 * h) ^ ((row & 3) << 3))];
#pragma unroll
      for (int ct = 0; ct < 3; ++ct)
        C[rt][ct] = __builtin_amdgcn_mfma_f32_16x16x32_bf16(a, bfr[ct], C[rt][ct], 0, 0, 0);
    }
  }
  float bb[3];
#pragma unroll
  for (int ct = 0; ct < 3; ++ct) bb[ct] = bias[16 * ct + q];
#pragma unroll
  for (int rt = 0; rt < 2; ++rt)
#pragma unroll
    for (int ct = 0; ct < 3; ++ct)
#pragma unroll
      for (int r = 0; r < 4; ++r) {
        const int row = r0 + 32 * w + 16 * rt + 4 * h + r;
        em[(size_t)row * T_DIM + 16 * ct + q] = C[rt][ct][r] + bb[ct];
      }
}

// ---------------------------------------------------------------------------
// K2: tree level 1 — chunk of 16 leaves: P_c = A_s1 ... A_s16,
// A_s = expT * diag(exp(em_s)).  M <- (M . expT) col-scaled; B = const expT frags.
// 128*32 blocks x 64 thr (1 wave).
// ---------------------------------------------------------------------------
__global__ __launch_bounds__(64) void k_tree1(
    const float* __restrict__ em, const short* __restrict__ expTcm,
    short* __restrict__ nodes1, int* __restrict__ exp1) {
  const int b = blockIdx.x >> 5, c = blockIdx.x & 31;
  const int l = threadIdx.x, h = l >> 4, q = l & 15;
  __shared__ short Ml[48 * 64];
  zero_lds(Ml, l);  // k>=48 swizzle slots must be 0 (read by A-frags, paired with B=0)

  Frags6 B;
  load_child(expTcm, h, q, B);

  const int s0 = 1 + 16 * c;
  const int NT = min(16, 511 - 16 * c);
  size_t ro = (size_t)(s0 * B_DIM + b) * T_DIM;
  float eA0 = em[ro + q], eA1 = em[ro + 16 + q], eA2 = em[ro + 32 + q];
  float eB0 = 0.f, eB1 = 0.f, eB2 = 0.f;

  f32x4 C[3][3];
  for (int t = 0; t < NT; ++t) {
    if (t + 1 < NT) {  // prefetch next emissions row
      size_t rn = (size_t)((s0 + t + 1) * B_DIM + b) * T_DIM;
      eB0 = em[rn + q]; eB1 = em[rn + 16 + q]; eB2 = em[rn + 32 + q];
    }
#pragma unroll
    for (int rt = 0; rt < 3; ++rt)
#pragma unroll
      for (int ct = 0; ct < 3; ++ct) C[rt][ct] = 0.f;
    matstep(Ml, t == 0, h, q, B, C);
    const float e0 = __expf(eA0), e1 = __expf(eA1), e2 = __expf(eA2);
#pragma unroll
    for (int rt = 0; rt < 3; ++rt)
#pragma unroll
      for (int r = 0; r < 4; ++r) {
        C[rt][0][r] *= e0; C[rt][1][r] *= e1; C[rt][2][r] *= e2;
      }
    writeM(Ml, h, q, C);
    eA0 = eB0; eA1 = eB1; eA2 = eB2;
  }
  int ex = store_node(nodes1 + (size_t)(b * 32 + c) * 2304, h, q, C);
  if (l == 0) exp1[b * 32 + c] = ex;
}

// ---------------------------------------------------------------------------
// K3: tree level 2 — product of 8 level-1 nodes.  128*4 blocks x 64 thr.
// ---------------------------------------------------------------------------
__global__ __launch_bounds__(64) void k_tree2(
    const short* __restrict__ nodes1, const int* __restrict__ exp1,
    short* __restrict__ nodes2, int* __restrict__ exp2) {
  const int b = blockIdx.x >> 2, c2 = blockIdx.x & 3;
  const int l = threadIdx.x, h = l >> 4, q = l & 15;
  __shared__ short Ml[48 * 64];
  zero_lds(Ml, l);

  const short* base = nodes1 + (size_t)(b * 32 + 8 * c2) * 2304;
  Frags6 B, Bn;
  load_child(base, h, q, B);
  f32x4 C[3][3];
  for (int t = 0; t < 8; ++t) {
    if (t < 7) load_child(base + (size_t)(t + 1) * 2304, h, q, Bn);
#pragma unroll
    for (int rt = 0; rt < 3; ++rt)
#pragma unroll
      for (int ct = 0; ct < 3; ++ct) C[rt][ct] = 0.f;
    matstep(Ml, t == 0, h, q, B, C);
    if (t < 7) { writeM(Ml, h, q, C); B = Bn; }
  }
  int ex = store_node(nodes2 + (size_t)(b * 4 + c2) * 2304, h, q, C);
  int ce = (l < 8) ? exp1[b * 32 + 8 * c2 + l] : 0;
  ce += __shfl_xor(ce, 1, 64); ce += __shfl_xor(ce, 2, 64); ce += __shfl_xor(ce, 4, 64);
  if (l == 0) exp2[b * 4 + c2] = ex + ce;
}

// ---------------------------------------------------------------------------
// K4: tree level 3 (4 nodes -> P) + log_Z + gold score + nll atomicAdd.
// 128 blocks x 64 thr.
// ---------------------------------------------------------------------------
__global__ __launch_bounds__(64) void k_tree3(
    const short* __restrict__ nodes2, const int* __restrict__ exp2,
    const float* __restrict__ em, const float* __restrict__ trans,
    const int* __restrict__ tags, float* __restrict__ out) {
  const int b = blockIdx.x;
  const int l = threadIdx.x, h = l >> 4, q = l & 15;
  __shared__ short Ml[48 * 64];
  zero_lds(Ml, l);

  const short* base = nodes2 + (size_t)(b * 4) * 2304;
  Frags6 B, Bn;
  load_child(base, h, q, B);
  f32x4 C[3][3];
  for (int t = 0; t < 4; ++t) {
    if (t < 3) load_child(base + (size_t)(t + 1) * 2304, h, q, Bn);
#pragma unroll
    for (int rt = 0; rt < 3; ++rt)
#pragma unroll
      for (int ct = 0; ct < 3; ++ct) C[rt][ct] = 0.f;
    matstep(Ml, t == 0, h, q, B, C);
    if (t < 3) { writeM(Ml, h, q, C); B = Bn; }
  }
  // Z = sum_i u0[i] * rowsum_i(P);  P in C (fp32, unscaled at this level)
  float Zp = 0.f;
#pragma unroll
  for (int rt = 0; rt < 3; ++rt)
#pragma unroll
    for (int r = 0; r < 4; ++r) {
      float rs = C[rt][0][r] + C[rt][1][r] + C[rt][2][r];
      rs += __shfl_xor(rs, 1, 64); rs += __shfl_xor(rs, 2, 64);
      rs += __shfl_xor(rs, 4, 64); rs += __shfl_xor(rs, 8, 64);
      const int row = 16 * rt + 4 * h + r;
      Zp = fmaf(__expf(em[(size_t)b * T_DIM + row]), rs, Zp);
    }
  Zp += __shfl_xor(Zp, 16, 64); Zp += __shfl_xor(Zp, 32, 64);
  int E = (l < 4) ? exp2[b * 4 + l] : 0;
  E += __shfl_xor(E, 1, 64); E += __shfl_xor(E, 2, 64);
  const float logZ = __logf(Zp) + (float)E * 0.69314718055994531f;

  // gold path score
  float g = 0.f;
  for (int s = l; s < S_DIM; s += 64) {
    const int tg = tags[s * B_DIM + b];
    g += em[(size_t)(s * B_DIM + b) * T_DIM + tg];
    if (s < S_DIM - 1) {
      const int tn = tags[(s + 1) * B_DIM + b];
      g += trans[tg * T_DIM + tn];
    }
  }
#pragma unroll
  for (int off = 1; off < 64; off <<= 1) g += __shfl_xor(g, off, 64);
  if (l == 0) atomicAdd(out, (logZ - g) * (1.0f / (float)B_DIM));
}

// ---------------------------------------------------------------------------
extern "C" void kernel_launch(void* const* d_in, const int* in_sizes, int n_in,
                              void* d_out, int out_size, void* d_ws, size_t ws_size,
                              hipStream_t stream) {
  const float* wf    = (const float*)d_in[0];
  const float* W     = (const float*)d_in[1];
  const float* bias  = (const float*)d_in[2];
  const float* trans = (const float*)d_in[3];
  const int*   tags  = (const int*)d_in[4];
  float* out = (float*)d_out;

  char* p = (char*)d_ws;
  float* em     = (float*)p;            p += (size_t)S_DIM * B_DIM * T_DIM * 4;  // 12.6 MB
  short* nodes1 = (short*)p;            p += (size_t)128 * 32 * 2304 * 2;        // 18.9 MB
  short* nodes2 = (short*)p;            p += (size_t)128 * 4 * 2304 * 2;         // 2.36 MB
  short* Wbf    = (short*)p;            p += (size_t)T_DIM * H_DIM * 2;
  short* expTcm = (short*)p;            p += (size_t)48 * 48 * 2 + 32;
  int*   exp1   = (int*)p;              p += 128 * 32 * 4;
  int*   exp2   = (int*)p;

  k_prep<<<32, 256, 0, stream>>>(W, trans, Wbf, expTcm, out);
  k_emissions<<<512, 256, 0, stream>>>(wf, Wbf, bias, em);
  k_tree1<<<128 * 32, 64, 0, stream>>>(em, expTcm, nodes1, exp1);
  k_tree2<<<128 * 4, 64, 0, stream>>>(nodes1, exp1, nodes2, exp2);
  k_tree3<<<128, 64, 0, stream>>>(nodes2, exp2, em, trans, tags, out);
}

// Round 6
// 253.843 us; speedup vs baseline: 1.5792x; 1.0102x over previous
//
#include <hip/hip_runtime.h>
#include <math.h>

#define S_DIM 512
#define B_DIM 128
#define H_DIM 512
#define T_DIM 48

typedef short bf16x8 __attribute__((ext_vector_type(8)));   // 8 bf16 = 4 VGPR (MFMA A/B frag)
typedef short s16x4  __attribute__((ext_vector_type(4)));
typedef float f32x4  __attribute__((ext_vector_type(4)));   // MFMA C/D frag

__device__ __forceinline__ short rne_bf(float f) {  // fp32 -> bf16 round-nearest-even
  unsigned u = __float_as_uint(f);
  u += 0x7fffu + ((u >> 16) & 1u);
  return (short)(u >> 16);
}
__device__ __forceinline__ short trunc_bf(float f) {  // cheap truncation (hot path)
  return (short)(__float_as_uint(f) >> 16);
}
__device__ __forceinline__ bf16x8 cvt8(const float* __restrict__ p) {  // 8 fp32 -> bf16x8
  float4 v0 = *(const float4*)p, v1 = *(const float4*)(p + 4);
  bf16x8 r;
  r[0] = rne_bf(v0.x); r[1] = rne_bf(v0.y); r[2] = rne_bf(v0.z); r[3] = rne_bf(v0.w);
  r[4] = rne_bf(v1.x); r[5] = rne_bf(v1.y); r[6] = rne_bf(v1.z); r[7] = rne_bf(v1.w);
  return r;
}

// ---------------------------------------------------------------------------
// Node format: 48x48 bf16, COLUMN-major: node[j*48 + k] = M[k][j].
// B-frag source: lane reads 8 consecutive k at fixed column j = 16ct+q.
// ---------------------------------------------------------------------------
struct Frags6 { bf16x8 b[2][3]; };  // [kstep][coltile]

__device__ __forceinline__ void load_child(const short* __restrict__ p, int h, int q, Frags6& f) {
  bf16x8 z = 0;
#pragma unroll
  for (int ct = 0; ct < 3; ++ct) {
    const short* col = p + (16 * ct + q) * 48;
    f.b[0][ct] = *(const bf16x8*)(col + 8 * h);                       // k = 8h..8h+7 (<32)
    f.b[1][ct] = (h < 2) ? *(const bf16x8*)(col + 32 + 8 * h) : z;    // k = 32..47, pad 0
  }
}

// one product step: C = A x B, A = (useI ? I48 : M in LDS), 18 MFMA, C fully overwritten
// Ml: [48 rows][64 k] bf16, short idx = row*64 + (k ^ ((row&7)<<3))  (XOR swizzle)
__device__ __forceinline__ void matstep(const short* Ml, bool useI, int h, int q,
                                        const Frags6& B, f32x4 C[3][3]) {
  const f32x4 Z = {0.f, 0.f, 0.f, 0.f};
#pragma unroll
  for (int rt = 0; rt < 3; ++rt) {
    const int row = 16 * rt + q;
    bf16x8 a0, a1;
    if (useI) {
      const short one = (short)0x3F80;  // bf16 1.0
#pragma unroll
      for (int i = 0; i < 8; ++i) {
        a0[i] = (row == 8 * h + i) ? one : (short)0;
        a1[i] = (row == 32 + 8 * h + i) ? one : (short)0;
      }
    } else {
      const int sw = (row & 7) << 3;
      a0 = *(const bf16x8*)&Ml[row * 64 + ((8 * h) ^ sw)];
      a1 = *(const bf16x8*)&Ml[row * 64 + ((32 + 8 * h) ^ sw)];
    }
#pragma unroll
    for (int ct = 0; ct < 3; ++ct)
      C[rt][ct] = __builtin_amdgcn_mfma_f32_16x16x32_bf16(
          a1, B.b[1][ct],
          __builtin_amdgcn_mfma_f32_16x16x32_bf16(a0, B.b[0][ct], Z, 0, 0, 0), 0, 0, 0);
  }
}

// write C (fp32) back into M LDS as bf16.  D-frag: row = 16rt+4h+r, col = 16ct+q.
__device__ __forceinline__ void writeM(short* Ml, int h, int q, const f32x4 C[3][3]) {
#pragma unroll
  for (int rt = 0; rt < 3; ++rt)
#pragma unroll
    for (int ct = 0; ct < 3; ++ct) {
      const int j = 16 * ct + q;
#pragma unroll
      for (int r = 0; r < 4; ++r) {
        const int row = 16 * rt + 4 * h + r;
        Ml[row * 64 + (j ^ ((row & 7) << 3))] = trunc_bf(C[rt][ct][r]);
      }
    }
}

// store C to a col-major node (values assumed already in range)
__device__ __forceinline__ void storecol(short* __restrict__ node, int h, int q,
                                         const f32x4 C[3][3]) {
#pragma unroll
  for (int rt = 0; rt < 3; ++rt)
#pragma unroll
    for (int ct = 0; ct < 3; ++ct) {
      s16x4 pk;
#pragma unroll
      for (int r = 0; r < 4; ++r) pk[r] = rne_bf(C[rt][ct][r]);
      *(s16x4*)&node[(16 * ct + q) * 48 + 16 * rt + 4 * h] = pk;
    }
}

// wave-wide rescale of C so max in [0.5,1); exact power of 2, returns exponent
__device__ __forceinline__ int rescaleC(f32x4 C[3][3]) {
  float mx = 0.f;
#pragma unroll
  for (int rt = 0; rt < 3; ++rt)
#pragma unroll
    for (int ct = 0; ct < 3; ++ct)
#pragma unroll
      for (int r = 0; r < 4; ++r) mx = fmaxf(mx, C[rt][ct][r]);
#pragma unroll
  for (int off = 1; off < 64; off <<= 1) mx = fmaxf(mx, __shfl_xor(mx, off, 64));
  int ex;
  frexpf(mx, &ex);
  const float sc = ldexpf(1.0f, -ex);
#pragma unroll
  for (int rt = 0; rt < 3; ++rt)
#pragma unroll
    for (int ct = 0; ct < 3; ++ct)
#pragma unroll
      for (int r = 0; r < 4; ++r) C[rt][ct][r] *= sc;
  return ex;
}

// rescale + store col-major node; returns exponent
__device__ __forceinline__ int store_node(short* __restrict__ node, int h, int q,
                                          f32x4 C[3][3]) {
  int ex = rescaleC(C);
  storecol(node, h, q, C);
  return ex;
}

__device__ __forceinline__ void zero_lds(short* Ml, int l) {
  s16x4 z = 0;
#pragma unroll
  for (int i = 0; i < 12; ++i) *(s16x4*)&Ml[(l + 64 * i) * 4] = z;  // 48*64 shorts
}

// ---------------------------------------------------------------------------
// K1: emissions via bf16 MFMA, A-frags streamed DIRECTLY from global (no LDS).
// em[row][t] = wf[row,:] . W[t,:] + b[t], fp32 out.  Also zeroes out[0].
// 512 blocks x 256 thr; wave w: rows 32w..32w+31 (2 rowtiles x 3 coltiles).
// ---------------------------------------------------------------------------
__global__ __launch_bounds__(256) void k_emissions(
    const float* __restrict__ wf, const float* __restrict__ W,
    const float* __restrict__ bias, float* __restrict__ em,
    float* __restrict__ out) {
  if (blockIdx.x == 0 && threadIdx.x == 0) out[0] = 0.0f;
  const int tid = threadIdx.x;
  const int w = tid >> 6, l = tid & 63, h = l >> 4, q = l & 15;
  const size_t r0 = (size_t)blockIdx.x * 128;

  f32x4 C[2][3];
#pragma unroll
  for (int rt = 0; rt < 2; ++rt)
#pragma unroll
    for (int ct = 0; ct < 3; ++ct) C[rt][ct] = 0.f;

  for (int ks = 0; ks < 16; ++ks) {
    const int k0 = 32 * ks + 8 * h;
    bf16x8 a[2], bb[3];
#pragma unroll
    for (int rt = 0; rt < 2; ++rt)
      a[rt] = cvt8(&wf[(r0 + 32 * w + 16 * rt + q) * H_DIM + k0]);
#pragma unroll
    for (int ct = 0; ct < 3; ++ct)
      bb[ct] = cvt8(&W[(size_t)(16 * ct + q) * H_DIM + k0]);
#pragma unroll
    for (int rt = 0; rt < 2; ++rt)
#pragma unroll
      for (int ct = 0; ct < 3; ++ct)
        C[rt][ct] = __builtin_amdgcn_mfma_f32_16x16x32_bf16(a[rt], bb[ct], C[rt][ct], 0, 0, 0);
  }
  float bv[3];
#pragma unroll
  for (int ct = 0; ct < 3; ++ct) bv[ct] = bias[16 * ct + q];
#pragma unroll
  for (int rt = 0; rt < 2; ++rt)
#pragma unroll
    for (int ct = 0; ct < 3; ++ct)
#pragma unroll
      for (int r = 0; r < 4; ++r) {
        const size_t row = r0 + 32 * w + 16 * rt + 4 * h + r;
        em[row * T_DIM + 16 * ct + q] = C[rt][ct][r] + bv[ct];
      }
}

// ---------------------------------------------------------------------------
// K2: tree level 1 — chunk of 16 leaves: N_c = A_s1 ... A_s16,
// A_s = expT * diag(exp(em_s)).  expT B-frags built from trans inline.
// 128*32 blocks x 64 thr (1 wave).
// ---------------------------------------------------------------------------
__global__ __launch_bounds__(64) void k_tree1(
    const float* __restrict__ em, const float* __restrict__ trans,
    short* __restrict__ nodes1, int* __restrict__ exp1) {
  const int b = blockIdx.x >> 5, c = blockIdx.x & 31;
  const int l = threadIdx.x, h = l >> 4, q = l & 15;
  __shared__ short Ml[48 * 64];
  zero_lds(Ml, l);  // k>=48 swizzle slots must stay 0

  // B = expT frags: element = exp(trans[k][16ct+q]), k = 32m+8h+i
  Frags6 B;
#pragma unroll
  for (int ct = 0; ct < 3; ++ct) {
    const int j = 16 * ct + q;
#pragma unroll
    for (int i = 0; i < 8; ++i) {
      const int k0 = 8 * h + i;
      B.b[0][ct][i] = rne_bf(__expf(trans[k0 * T_DIM + j]));
      const int k1 = 32 + 8 * h + i;
      B.b[1][ct][i] = (k1 < T_DIM) ? rne_bf(__expf(trans[k1 * T_DIM + j])) : (short)0;
    }
  }

  const int s0 = 1 + 16 * c;
  const int NT = min(16, 511 - 16 * c);
  size_t ro = (size_t)(s0 * B_DIM + b) * T_DIM;
  float eA0 = __expf(em[ro + q]), eA1 = __expf(em[ro + 16 + q]), eA2 = __expf(em[ro + 32 + q]);
  float eB0 = 0.f, eB1 = 0.f, eB2 = 0.f;

  f32x4 C[3][3];
  for (int t = 0; t < NT; ++t) {
    if (t + 1 < NT) {  // prefetch + exp off the critical path
      size_t rn = (size_t)((s0 + t + 1) * B_DIM + b) * T_DIM;
      eB0 = __expf(em[rn + q]); eB1 = __expf(em[rn + 16 + q]); eB2 = __expf(em[rn + 32 + q]);
    }
    matstep(Ml, t == 0, h, q, B, C);
#pragma unroll
    for (int rt = 0; rt < 3; ++rt)
#pragma unroll
      for (int r = 0; r < 4; ++r) {
        C[rt][0][r] *= eA0; C[rt][1][r] *= eA1; C[rt][2][r] *= eA2;
      }
    writeM(Ml, h, q, C);
    eA0 = eB0; eA1 = eB1; eA2 = eB2;
  }
  int ex = store_node(nodes1 + (size_t)(b * 32 + c) * 2304, h, q, C);
  if (l == 0) exp1[b * 32 + c] = ex;
}

// ---------------------------------------------------------------------------
// K3: final — merge 32 nodes (4 waves x 8 serial, RESCALE at wave boundary,
// then wave0 folds 3 partners), log_Z, gold path score, nll atomicAdd.
// 128 blocks x 256 thr.
// ---------------------------------------------------------------------------
__global__ __launch_bounds__(256) void k_final(
    const short* __restrict__ nodes1, const int* __restrict__ exp1,
    const float* __restrict__ em, const float* __restrict__ trans,
    const int* __restrict__ tags, float* __restrict__ out) {
  const int b = blockIdx.x, tid = threadIdx.x;
  const int v = tid >> 6, l = tid & 63, h = l >> 4, q = l & 15;
  __shared__ short Ml[4][48 * 64];
  __shared__ short Pc[3][2304];
  __shared__ float gred[4];
  __shared__ int wexp[4];

  // gold path score (all 256 threads)
  float g = 0.f;
  for (int s = tid; s < S_DIM; s += 256) {
    const int tg = tags[s * B_DIM + b];
    g += em[(size_t)(s * B_DIM + b) * T_DIM + tg];
    if (s < S_DIM - 1) g += trans[tg * T_DIM + tags[(s + 1) * B_DIM + b]];
  }
#pragma unroll
  for (int off = 1; off < 64; off <<= 1) g += __shfl_xor(g, off, 64);
  if (l == 0) gred[v] = g;

  // wave v: Q_v = N_{8v} ... N_{8v+7}
  zero_lds(Ml[v], l);
  const short* base = nodes1 + (size_t)(b * 32 + 8 * v) * 2304;
  Frags6 B, Bn;
  load_child(base, h, q, B);
  f32x4 C[3][3];
  for (int t = 0; t < 8; ++t) {
    if (t < 7) load_child(base + (size_t)(t + 1) * 2304, h, q, Bn);
    matstep(Ml[v], t == 0, h, q, B, C);
    if (t < 7) { writeM(Ml[v], h, q, C); B = Bn; }
  }
  // rescale Q_v to max in [0.5,1) — prevents fp32 overflow in the fold
  // (round-4 bug: unrescaled Q1..Q3 compounded to ~1e43 -> inf)
  int ex = rescaleC(C);
  if (l == 0) wexp[v] = ex;
  if (v > 0) storecol(Pc[v - 1], h, q, C);
  else       writeM(Ml[0], h, q, C);
  __syncthreads();

  if (v == 0) {
    // P = Q0 * Q1 * Q2 * Q3  (all rescaled; worst-case growth <= 48^3)
    for (int t = 0; t < 3; ++t) {
      load_child(Pc[t], h, q, B);
      matstep(Ml[0], false, h, q, B, C);
      if (t < 2) writeM(Ml[0], h, q, C);
    }
    // Z = sum_i exp(em[0,b,i]) * rowsum_i(P)
    float Zp = 0.f;
#pragma unroll
    for (int rt = 0; rt < 3; ++rt)
#pragma unroll
      for (int r = 0; r < 4; ++r) {
        float rs = C[rt][0][r] + C[rt][1][r] + C[rt][2][r];
        rs += __shfl_xor(rs, 1, 64); rs += __shfl_xor(rs, 2, 64);
        rs += __shfl_xor(rs, 4, 64); rs += __shfl_xor(rs, 8, 64);
        const int row = 16 * rt + 4 * h + r;
        Zp = fmaf(__expf(em[(size_t)b * T_DIM + row]), rs, Zp);
      }
    Zp += __shfl_xor(Zp, 16, 64); Zp += __shfl_xor(Zp, 32, 64);
    int E = (l < 32) ? exp1[b * 32 + l] : 0;
#pragma unroll
    for (int off = 1; off < 32; off <<= 1) E += __shfl_xor(E, off, 64);
    E += wexp[0] + wexp[1] + wexp[2] + wexp[3];
    const float logZ = __logf(Zp) + (float)E * 0.69314718055994531f;
    const float gold = gred[0] + gred[1] + gred[2] + gred[3];
    if (l == 0) atomicAdd(out, (logZ - gold) * (1.0f / (float)B_DIM));
  }
}

// ---------------------------------------------------------------------------
extern "C" void kernel_launch(void* const* d_in, const int* in_sizes, int n_in,
                              void* d_out, int out_size, void* d_ws, size_t ws_size,
                              hipStream_t stream) {
  const float* wf    = (const float*)d_in[0];
  const float* W     = (const float*)d_in[1];
  const float* bias  = (const float*)d_in[2];
  const float* trans = (const float*)d_in[3];
  const int*   tags  = (const int*)d_in[4];
  float* out = (float*)d_out;

  char* p = (char*)d_ws;
  float* em     = (float*)p;  p += (size_t)S_DIM * B_DIM * T_DIM * 4;  // 12.6 MB
  short* nodes1 = (short*)p;  p += (size_t)128 * 32 * 2304 * 2;        // 18.9 MB
  int*   exp1   = (int*)p;

  k_emissions<<<512, 256, 0, stream>>>(wf, W, bias, em, out);
  k_tree1<<<128 * 32, 64, 0, stream>>>(em, trans, nodes1, exp1);
  k_final<<<128, 256, 0, stream>>>(nodes1, exp1, em, trans, tags, out);
}